// Round 6
// baseline (259.735 us; speedup 1.0000x reference)
//
#include <hip/hip_runtime.h>
#include <stdint.h>

#define B_SZ 2
#define T_SZ 2048
#define C_SZ 1024
#define NH   16
#define NKV  4
#define HD   64
#define KVD  256
#define QKV_N 1536

typedef __attribute__((ext_vector_type(8))) short bf16x8;
typedef __attribute__((ext_vector_type(4))) float f32x4;

#define GL(p) ((const __attribute__((address_space(1))) void*)(p))
#define LD(p) ((__attribute__((address_space(3))) void*)(p))

__device__ inline unsigned short f2bf(float f) {
  union { float f; unsigned u; } v; v.f = f;
  unsigned u = v.u;
  unsigned r = (u + 0x7fffu + ((u >> 16) & 1u)) >> 16;
  return (unsigned short)r;
}
__device__ inline unsigned short bftrunc(float f) {  // truncate: 1 inst; bias cancels in O/l
  union { float f; unsigned u; } v; v.f = f;
  return (unsigned short)(v.u >> 16);
}

// ---------------- fused fp32->bf16 convert (5 segments) + gate precompute, 1 launch ----------------
struct CvtArgs {
  const float *s0, *s1, *s2, *s3, *s4;
  unsigned short *d0, *d1, *d2, *d3, *d4;
  const float *x, *Wg;
  float *gate;           // [B*T][NKV]
};
__global__ __launch_bounds__(256) void cvt_all(CvtArgs a) {
  int blk = blockIdx.x, tid = threadIdx.x;
  if (blk >= 6656) {  // gate: 3*sigmoid(x[:, :12] @ Wg^T)
    int idx = (blk - 6656) * 256 + tid;
    int bt = idx >> 2, kh = idx & 3;
    float s = 0.f;
#pragma unroll
    for (int j = 0; j < 12; j++) s += a.x[(size_t)bt * C_SZ + j] * a.Wg[kh * 12 + j];
    a.gate[idx] = 3.f / (1.f + __expf(-s));
    return;
  }
  const float* s; unsigned short* d; int i;
  if      (blk < 4096) { s = a.s0; d = a.d0; i = blk * 256 + tid; }
  else if (blk < 5120) { s = a.s1; d = a.d1; i = (blk - 4096) * 256 + tid; }
  else if (blk < 5376) { s = a.s2; d = a.d2; i = (blk - 5120) * 256 + tid; }
  else if (blk < 5632) { s = a.s3; d = a.d3; i = (blk - 5376) * 256 + tid; }
  else                 { s = a.s4; d = a.d4; i = (blk - 5632) * 256 + tid; }
  float4 f = ((const float4*)s)[i];
  ushort4 o;
  o.x = f2bf(f.x); o.y = f2bf(f.y); o.z = f2bf(f.z); o.w = f2bf(f.w);
  ((ushort4*)d)[i] = o;
}

// ========== GEMM core: 64x128 tile, BK=64, single-barrier ping-pong dbuf, XOR-swizzled LDS ==========
// (round-0 proven config: 768/512 blocks -> 3/2 blocks/CU co-residency hides barrier drain)
#define GEMM_PROLOG(A, Bm, K)                                                        \
  __shared__ unsigned short As[2][64 * 64];                                          \
  __shared__ unsigned short Bs[2][128 * 64];                                         \
  int tid  = threadIdx.x;                                                            \
  int lane = tid & 63;                                                               \
  int wave = tid >> 6;                                                               \
  int quad = lane >> 4;                                                              \
  int l16  = lane & 15;                                                              \
  int m0 = blockIdx.y * 64;                                                          \
  int n0 = blockIdx.x * 128;                                                         \
  int wm = (wave & 1) * 32;                                                          \
  int wn = (wave >> 1) * 64;                                                         \
  f32x4 acc[2][4];                                                                   \
  _Pragma("unroll") for (int i = 0; i < 2; i++)                                      \
    _Pragma("unroll") for (int j = 0; j < 4; j++)                                    \
      acc[i][j] = (f32x4){0.f, 0.f, 0.f, 0.f};                                       \
  int lrow = lane >> 3;                              /* 0..7 within 8-row block */   \
  int lcol = ((lane & 7) ^ lrow) * 8;                /* XOR-swizzled source chunk */ \
  int sA = wave * 16;                                                                \
  int sB = wave * 32;                                                                \
  const unsigned short* aP0 = &A[(size_t)(m0 + sA + lrow) * K + lcol];               \
  const unsigned short* aP1 = aP0 + 8 * (size_t)K;                                   \
  const unsigned short* bP0 = &Bm[(size_t)(n0 + sB + lrow) * K + lcol];              \
  const unsigned short* bP1 = bP0 + 8 * (size_t)K;                                   \
  const unsigned short* bP2 = bP0 + 16 * (size_t)K;                                  \
  const unsigned short* bP3 = bP0 + 24 * (size_t)K;                                  \
  __builtin_amdgcn_global_load_lds(GL(aP0), LD(&As[0][(sA     ) * 64]), 16, 0, 0);   \
  __builtin_amdgcn_global_load_lds(GL(aP1), LD(&As[0][(sA +  8) * 64]), 16, 0, 0);   \
  __builtin_amdgcn_global_load_lds(GL(bP0), LD(&Bs[0][(sB     ) * 64]), 16, 0, 0);   \
  __builtin_amdgcn_global_load_lds(GL(bP1), LD(&Bs[0][(sB +  8) * 64]), 16, 0, 0);   \
  __builtin_amdgcn_global_load_lds(GL(bP2), LD(&Bs[0][(sB + 16) * 64]), 16, 0, 0);   \
  __builtin_amdgcn_global_load_lds(GL(bP3), LD(&Bs[0][(sB + 24) * 64]), 16, 0, 0);   \
  int swz = l16 & 7;                                                                 \
  int nk = K >> 6;                                                                   \
  for (int ki = 0; ki < nk; ki++) {                                                  \
    int cur = ki & 1, nxt = cur ^ 1;                                                 \
    __syncthreads();                                                                 \
    if (ki + 1 < nk) {                                                               \
      int k0 = (ki + 1) << 6;                                                        \
      __builtin_amdgcn_global_load_lds(GL(aP0 + k0), LD(&As[nxt][(sA     ) * 64]), 16, 0, 0); \
      __builtin_amdgcn_global_load_lds(GL(aP1 + k0), LD(&As[nxt][(sA +  8) * 64]), 16, 0, 0); \
      __builtin_amdgcn_global_load_lds(GL(bP0 + k0), LD(&Bs[nxt][(sB     ) * 64]), 16, 0, 0); \
      __builtin_amdgcn_global_load_lds(GL(bP1 + k0), LD(&Bs[nxt][(sB +  8) * 64]), 16, 0, 0); \
      __builtin_amdgcn_global_load_lds(GL(bP2 + k0), LD(&Bs[nxt][(sB + 16) * 64]), 16, 0, 0); \
      __builtin_amdgcn_global_load_lds(GL(bP3 + k0), LD(&Bs[nxt][(sB + 24) * 64]), 16, 0, 0); \
    }                                                                                \
    _Pragma("unroll") for (int p = 0; p < 2; p++) {                                  \
      bf16x8 af[2], bfr[4];                                                          \
      _Pragma("unroll") for (int i = 0; i < 2; i++)                                  \
        af[i] = *(const bf16x8*)&As[cur][(wm + i * 16 + l16) * 64 + (((p * 4 + quad) ^ swz) * 8)]; \
      _Pragma("unroll") for (int j = 0; j < 4; j++)                                  \
        bfr[j] = *(const bf16x8*)&Bs[cur][(wn + j * 16 + l16) * 64 + (((p * 4 + quad) ^ swz) * 8)]; \
      _Pragma("unroll") for (int i = 0; i < 2; i++)                                  \
        _Pragma("unroll") for (int j = 0; j < 4; j++)                                \
          acc[i][j] = __builtin_amdgcn_mfma_f32_16x16x32_bf16(af[i], bfr[j], acc[i][j], 0, 0, 0); \
    }                                                                                \
  }

// ---------------- gemm2: C[m,n] = sum_k A[m,k]*B[n,k], fp32 out ----------------
__global__ __launch_bounds__(256) void gemm_bt(const unsigned short* __restrict__ A,
                                               const unsigned short* __restrict__ Bm,
                                               float* __restrict__ C,
                                               int N, int K) {
  GEMM_PROLOG(A, Bm, K)
#pragma unroll
  for (int i = 0; i < 2; i++) {
#pragma unroll
    for (int j = 0; j < 4; j++) {
      int col = n0 + wn + j * 16 + l16;
#pragma unroll
      for (int r = 0; r < 4; r++) {
        int row = m0 + wm + i * 16 + quad * 4 + r;
        C[(size_t)row * N + col] = acc[i][j][r];
      }
    }
  }
}

// ---------------- gemm1 fused: qkv proj + RoPE + RMSNorm + gate*ve, bf16 out ----------------
// V written COALESCED row-major (bt, kh*64+d); v_transpose produces (B,NKV,HD,T).
__global__ __launch_bounds__(256) void gemm_qkv(const unsigned short* __restrict__ A,
                                                const unsigned short* __restrict__ Bm,
                                                const float* __restrict__ ve,
                                                const float* __restrict__ cosb,
                                                const float* __restrict__ sinb,
                                                const float* __restrict__ gateArr,
                                                unsigned short* __restrict__ qa,
                                                unsigned short* __restrict__ ka,
                                                unsigned short* __restrict__ vtmp) {
  const int K = C_SZ;
  GEMM_PROLOG(A, Bm, K)

  int colbase = n0 + wn;   // multiple of 64
  if (colbase < 1280) {    // Q or K head
    int isQ = colbase < 1024;
    int h   = isQ ? (colbase >> 6) : ((colbase - 1024) >> 6);
    float scale = isQ ? (0.15f * 1.44269504088896f) : 1.2f;
    unsigned short* dst = isQ ? qa : ka;
    int nheads = isQ ? NH : NKV;
#pragma unroll
    for (int i = 0; i < 2; i++) {
#pragma unroll
      for (int r = 0; r < 4; r++) {
        int row = m0 + wm + i * 16 + quad * 4 + r;   // bt
        int t = row & (T_SZ - 1), b = row >> 11;
        float a10 = acc[i][0][r], a11 = acc[i][1][r];
        float a20 = acc[i][2][r], a21 = acc[i][3][r];
        float cv0 = cosb[t * 32 + l16],      sv0 = sinb[t * 32 + l16];
        float cv1 = cosb[t * 32 + 16 + l16], sv1 = sinb[t * 32 + 16 + l16];
        float o10 =  a10 * cv0 + a20 * sv0;
        float o11 =  a11 * cv1 + a21 * sv1;
        float o20 = -a10 * sv0 + a20 * cv0;
        float o21 = -a11 * sv1 + a21 * cv1;
        float ssq = o10 * o10 + o11 * o11 + o20 * o20 + o21 * o21;
        ssq += __shfl_xor(ssq, 1);
        ssq += __shfl_xor(ssq, 2);
        ssq += __shfl_xor(ssq, 4);
        ssq += __shfl_xor(ssq, 8);
        float rn = rsqrtf(ssq * (1.f / 64.f) + 1e-6f) * scale;
        size_t base = ((size_t)(b * nheads + h) * T_SZ + t) * HD;
        dst[base + l16]      = f2bf(o10 * rn);
        dst[base + 16 + l16] = f2bf(o11 * rn);
        dst[base + 32 + l16] = f2bf(o20 * rn);
        dst[base + 48 + l16] = f2bf(o21 * rn);
      }
    }
  } else {                 // V head: add gate*ve, write coalesced (bt, kh*64+d)
    int kh = (colbase - 1280) >> 6;
#pragma unroll
    for (int i = 0; i < 2; i++) {
#pragma unroll
      for (int r = 0; r < 4; r++) {
        int row = m0 + wm + i * 16 + quad * 4 + r;   // bt
        float g = gateArr[row * 4 + kh];
#pragma unroll
        for (int j = 0; j < 4; j++) {
          int d = j * 16 + l16;
          float val = acc[i][j][r] + g * ve[(size_t)row * KVD + kh * HD + d];
          vtmp[(size_t)row * KVD + kh * HD + d] = f2bf(val);
        }
      }
    }
  }
}

// ---------------- V transpose: (B*T, NKV*HD) -> (B,NKV,HD,T), 64x64 LDS tiles ----------------
__global__ __launch_bounds__(256) void v_transpose(const unsigned short* __restrict__ vtmp,
                                                   unsigned short* __restrict__ vt) {
  __shared__ unsigned short tile[64 * 68];
  int blk = blockIdx.x;               // b(2) x kh(4) x tb(32)
  int tb = blk & 31, kh = (blk >> 5) & 3, b = blk >> 7;
  int tid = threadIdx.x;
  int r = tid >> 2, c = (tid & 3) * 16;
  const unsigned short* src = &vtmp[((size_t)(b * T_SZ + tb * 64 + r)) * KVD + kh * HD + c];
  uint4 x0 = *(const uint4*)(src);
  uint4 x1 = *(const uint4*)(src + 8);
  *(uint2*)&tile[r * 68 + c]      = *(uint2*)&x0;
  *(uint2*)&tile[r * 68 + c + 4]  = *((uint2*)&x0 + 1);
  *(uint2*)&tile[r * 68 + c + 8]  = *(uint2*)&x1;
  *(uint2*)&tile[r * 68 + c + 12] = *((uint2*)&x1 + 1);
  __syncthreads();
  int d = tid >> 2, tc = (tid & 3) * 16;
  ushort4 o0, o1, o2, o3;
  o0.x = tile[(tc + 0) * 68 + d];  o0.y = tile[(tc + 1) * 68 + d];
  o0.z = tile[(tc + 2) * 68 + d];  o0.w = tile[(tc + 3) * 68 + d];
  o1.x = tile[(tc + 4) * 68 + d];  o1.y = tile[(tc + 5) * 68 + d];
  o1.z = tile[(tc + 6) * 68 + d];  o1.w = tile[(tc + 7) * 68 + d];
  o2.x = tile[(tc + 8) * 68 + d];  o2.y = tile[(tc + 9) * 68 + d];
  o2.z = tile[(tc + 10) * 68 + d]; o2.w = tile[(tc + 11) * 68 + d];
  o3.x = tile[(tc + 12) * 68 + d]; o3.y = tile[(tc + 13) * 68 + d];
  o3.z = tile[(tc + 14) * 68 + d]; o3.w = tile[(tc + 15) * 68 + d];
  unsigned short* dst = &vt[((size_t)(b * NKV + kh) * HD + d) * T_SZ + tb * 64 + tc];
  *(ushort4*)(dst)      = o0;
  *(ushort4*)(dst + 4)  = o1;
  *(ushort4*)(dst + 8)  = o2;
  *(ushort4*)(dst + 12) = o3;
}

// ---------------- causal flash attention: Q=128, 8 waves x 16 q-rows, NO K/V staging ----------------
// K+V per (b,kh) = 512KB -> L2-fits (m169 regime): MFMA fragments are row-contiguous 16B in
// both ka [t][d] and vt [d][t], so read them DIRECTLY from global (L1 serves 8-way wave reuse;
// 16KB/iter working set). LDS keeps only the per-wave P transpose (16KB). No __syncthreads:
// no cross-wave data; raw s_barrier (no vmcnt/lgkm drain) keeps waves converged for L1 reuse.
// V-frag loads issue before the softmax VALU block so L2 latency hides under exp2/mask.
__global__ __launch_bounds__(512, 4) void attn(const unsigned short* __restrict__ qa,
                                               const unsigned short* __restrict__ ka,
                                               const unsigned short* __restrict__ vt,
                                               unsigned short* __restrict__ y) {
  // pair qt with 15-qt so co-resident blocks sum to equal work
  int bid = blockIdx.x;
  int half = bid >> 8, r = bid & 255;
  int qt = half ? (r & 15) : 15 - (r & 15);
  int bh = (half << 4) | (r >> 4);
  int b = bh >> 4, h = bh & 15;
  int kh = h >> 2;
  int tid = threadIdx.x;
  int wave = tid >> 6, lane = tid & 63;
  int quad = lane >> 4, l16 = lane & 15;
  int swz = l16 & 7;

  __shared__ unsigned short Ps[128 * 64];     // [q_local][t_local], per-wave 16-row regions
  unsigned short* Pw = &Ps[(wave * 16) * 64];

  int qrow0 = qt * 128 + wave * 16;

  bf16x8 bq0, bq1;
  {
    int tq = qrow0 + l16;
    const unsigned short* qp = &qa[((size_t)(b * NH + h) * T_SZ + tq) * HD];
    bq0 = *(const bf16x8*)&qp[quad * 8];
    bq1 = *(const bf16x8*)&qp[32 + quad * 8];
  }

  const unsigned short one_bf = 0x3F80;
  bf16x8 vones = {(short)one_bf, (short)one_bf, (short)one_bf, (short)one_bf,
                  (short)one_bf, (short)one_bf, (short)one_bf, (short)one_bf};

  f32x4 oacc[4];
  f32x4 lacc = (f32x4){0.f, 0.f, 0.f, 0.f};
#pragma unroll
  for (int d = 0; d < 4; d++) oacc[d] = (f32x4){0.f, 0.f, 0.f, 0.f};

  // per-lane fragment base offsets (elements)
  const unsigned short* kfrag = &ka[(size_t)(b * NKV + kh) * T_SZ * HD + (size_t)l16 * HD + quad * 8];
  const unsigned short* vfrag = &vt[(size_t)(b * NKV + kh) * HD * T_SZ + (size_t)l16 * T_SZ + quad * 8];

  int nj = 2 * qt + 2;

  for (int j = 0; j < nj; j++) {
    __builtin_amdgcn_s_barrier();   // convergence only (L1 reuse); no cross-wave data

    // waves whose 16 q-rows all precede this K-block are fully masked -> skip compute
    bool active = (j * 64) <= (qrow0 + 15);
    if (!active) continue;

    int t0 = j * 64;

    // S^T = K Q^T: K-frags direct from global ([t][d] rows, 16B contiguous)
    f32x4 st[4];
#pragma unroll
    for (int tb = 0; tb < 4; tb++) {
      const unsigned short* kr = kfrag + (size_t)(t0 + tb * 16) * HD;
      bf16x8 ak0 = *(const bf16x8*)kr;
      bf16x8 ak1 = *(const bf16x8*)(kr + 32);
      f32x4 s = (f32x4){0.f, 0.f, 0.f, 0.f};
      s = __builtin_amdgcn_mfma_f32_16x16x32_bf16(ak0, bq0, s, 0, 0, 0);
      s = __builtin_amdgcn_mfma_f32_16x16x32_bf16(ak1, bq1, s, 0, 0, 0);
      st[tb] = s;
    }

    // V-frags issued now so their latency hides under the softmax VALU block
    bf16x8 vf0[4], vf1[4];
#pragma unroll
    for (int d = 0; d < 4; d++) {
      const unsigned short* vr = vfrag + (size_t)(d * 16) * T_SZ + t0;
      vf0[d] = *(const bf16x8*)vr;
      vf1[d] = *(const bf16x8*)(vr + 32);
    }

    // mask + exp2 + packed b64 store of P[q][t] (per-wave region)
    if (t0 + 63 > qrow0) {
      int qg = qrow0 + l16;
#pragma unroll
      for (int tb = 0; tb < 4; tb++) {
        int tg = t0 + tb * 16 + quad * 4;
#pragma unroll
        for (int i = 0; i < 4; i++) {
          if (tg + i > qg) st[tb][i] = -__builtin_inff();
        }
      }
    }
#pragma unroll
    for (int tb = 0; tb < 4; tb++) {
      ushort4 w;
      w.x = bftrunc(__builtin_amdgcn_exp2f(st[tb][0]));
      w.y = bftrunc(__builtin_amdgcn_exp2f(st[tb][1]));
      w.z = bftrunc(__builtin_amdgcn_exp2f(st[tb][2]));
      w.w = bftrunc(__builtin_amdgcn_exp2f(st[tb][3]));
      // t-offset tb*16+quad*4 -> chunk tb*2+(quad>>1), half (quad&1)*4
      *(ushort4*)&Pw[l16 * 64 + (((tb * 2 + (quad >> 1)) ^ swz) * 8) + (quad & 1) * 4] = w;
    }

    bf16x8 ap0 = *(const bf16x8*)&Pw[l16 * 64 + ((quad ^ swz) * 8)];
    bf16x8 ap1 = *(const bf16x8*)&Pw[l16 * 64 + (((4 + quad) ^ swz) * 8)];
    lacc = __builtin_amdgcn_mfma_f32_16x16x32_bf16(ap0, vones, lacc, 0, 0, 0);
    lacc = __builtin_amdgcn_mfma_f32_16x16x32_bf16(ap1, vones, lacc, 0, 0, 0);
#pragma unroll
    for (int d = 0; d < 4; d++) {
      oacc[d] = __builtin_amdgcn_mfma_f32_16x16x32_bf16(ap0, vf0[d], oacc[d], 0, 0, 0);
      oacc[d] = __builtin_amdgcn_mfma_f32_16x16x32_bf16(ap1, vf1[d], oacc[d], 0, 0, 0);
    }
  }

#pragma unroll
  for (int i = 0; i < 4; i++) {
    int tq = qrow0 + quad * 4 + i;
    float inv = 1.f / lacc[i];
#pragma unroll
    for (int d = 0; d < 4; d++) {
      y[((size_t)(b * T_SZ) + tq) * C_SZ + h * HD + d * 16 + l16] = f2bf(oacc[d][i] * inv);
    }
  }
}

extern "C" void kernel_launch(void* const* d_in, const int* in_sizes, int n_in,
                              void* d_out, int out_size, void* d_ws, size_t ws_size,
                              hipStream_t stream) {
  const float* x    = (const float*)d_in[0];
  const float* ve   = (const float*)d_in[1];
  const float* cosb = (const float*)d_in[2];
  const float* sinb = (const float*)d_in[3];
  const float* Wq   = (const float*)d_in[4];
  const float* Wk   = (const float*)d_in[5];
  const float* Wv   = (const float*)d_in[6];
  const float* Wo   = (const float*)d_in[7];
  const float* Wg   = (const float*)d_in[8];
  float* out = (float*)d_out;

  const size_t MB = 1024 * 1024;
  char* ws = (char*)d_ws;
  unsigned short* xb    = (unsigned short*)(ws);             // 8 MB (reused as yb)
  unsigned short* wqkvb = (unsigned short*)(ws + 8 * MB);    // 3 MB
  unsigned short* wob   = (unsigned short*)(ws + 11 * MB);   // 2 MB
  unsigned short* qab   = (unsigned short*)(ws + 13 * MB);   // 8 MB
  unsigned short* kab   = (unsigned short*)(ws + 21 * MB);   // 2 MB
  unsigned short* vtb   = (unsigned short*)(ws + 23 * MB);   // 2 MB
  float*          gateA = (float*)(ws + 25 * MB);            // 64 KB
  unsigned short* vtmp  = (unsigned short*)(ws + 26 * MB);   // 2 MB
  unsigned short* yb    = xb;                                // reuse after gemm_qkv

  CvtArgs ca;
  ca.s0 = x;  ca.d0 = xb;
  ca.s1 = Wq; ca.d1 = wqkvb;
  ca.s2 = Wk; ca.d2 = wqkvb + 1024 * 1024;
  ca.s3 = Wv; ca.d3 = wqkvb + 1280 * 1024;
  ca.s4 = Wo; ca.d4 = wob;
  ca.x = x; ca.Wg = Wg; ca.gate = gateA;
  cvt_all<<<6720, 256, 0, stream>>>(ca);

  gemm_qkv<<<dim3(QKV_N / 128, (B_SZ * T_SZ) / 64), 256, 0, stream>>>(
      xb, wqkvb, ve, cosb, sinb, gateA, qab, kab, vtmp);

  v_transpose<<<256, 256, 0, stream>>>(vtmp, vtb);

  attn<<<512, 512, 0, stream>>>(qab, kab, vtb, yb);

  gemm_bt<<<dim3(C_SZ / 128, (B_SZ * T_SZ) / 64), 256, 0, stream>>>(
      yb, wob, out, C_SZ, C_SZ);
}

// Round 7
// 161.352 us; speedup vs baseline: 1.6097x; 1.6097x over previous
//
#include <hip/hip_runtime.h>
#include <stdint.h>

#define B_SZ 2
#define T_SZ 2048
#define C_SZ 1024
#define NH   16
#define NKV  4
#define HD   64
#define KVD  256
#define QKV_N 1536

typedef __attribute__((ext_vector_type(8))) short bf16x8;
typedef __attribute__((ext_vector_type(4))) float f32x4;

#define GL(p) ((const __attribute__((address_space(1))) void*)(p))
#define LD(p) ((__attribute__((address_space(3))) void*)(p))

__device__ inline unsigned short f2bf(float f) {
  union { float f; unsigned u; } v; v.f = f;
  unsigned u = v.u;
  unsigned r = (u + 0x7fffu + ((u >> 16) & 1u)) >> 16;
  return (unsigned short)r;
}
__device__ inline unsigned short bftrunc(float f) {  // truncate: 1 inst; bias cancels in O/l
  union { float f; unsigned u; } v; v.f = f;
  return (unsigned short)(v.u >> 16);
}

// ---------------- fused fp32->bf16 convert (5 segments) + gate precompute, 1 launch ----------------
struct CvtArgs {
  const float *s0, *s1, *s2, *s3, *s4;
  unsigned short *d0, *d1, *d2, *d3, *d4;
  const float *x, *Wg;
  float *gate;           // [B*T][NKV]
};
__global__ __launch_bounds__(256) void cvt_all(CvtArgs a) {
  int blk = blockIdx.x, tid = threadIdx.x;
  if (blk >= 6656) {  // gate: 3*sigmoid(x[:, :12] @ Wg^T)
    int idx = (blk - 6656) * 256 + tid;
    int bt = idx >> 2, kh = idx & 3;
    float s = 0.f;
#pragma unroll
    for (int j = 0; j < 12; j++) s += a.x[(size_t)bt * C_SZ + j] * a.Wg[kh * 12 + j];
    a.gate[idx] = 3.f / (1.f + __expf(-s));
    return;
  }
  const float* s; unsigned short* d; int i;
  if      (blk < 4096) { s = a.s0; d = a.d0; i = blk * 256 + tid; }
  else if (blk < 5120) { s = a.s1; d = a.d1; i = (blk - 4096) * 256 + tid; }
  else if (blk < 5376) { s = a.s2; d = a.d2; i = (blk - 5120) * 256 + tid; }
  else if (blk < 5632) { s = a.s3; d = a.d3; i = (blk - 5376) * 256 + tid; }
  else                 { s = a.s4; d = a.d4; i = (blk - 5632) * 256 + tid; }
  float4 f = ((const float4*)s)[i];
  ushort4 o;
  o.x = f2bf(f.x); o.y = f2bf(f.y); o.z = f2bf(f.z); o.w = f2bf(f.w);
  ((ushort4*)d)[i] = o;
}

// ========== GEMM core: 64x128 tile, BK=64, single-barrier ping-pong dbuf, XOR-swizzled LDS ==========
// (round-0 proven config: 768/512 blocks -> 3/2 blocks/CU co-residency hides barrier drain)
#define GEMM_PROLOG(A, Bm, K)                                                        \
  __shared__ unsigned short As[2][64 * 64];                                          \
  __shared__ unsigned short Bs[2][128 * 64];                                         \
  int tid  = threadIdx.x;                                                            \
  int lane = tid & 63;                                                               \
  int wave = tid >> 6;                                                               \
  int quad = lane >> 4;                                                              \
  int l16  = lane & 15;                                                              \
  int m0 = blockIdx.y * 64;                                                          \
  int n0 = blockIdx.x * 128;                                                         \
  int wm = (wave & 1) * 32;                                                          \
  int wn = (wave >> 1) * 64;                                                         \
  f32x4 acc[2][4];                                                                   \
  _Pragma("unroll") for (int i = 0; i < 2; i++)                                      \
    _Pragma("unroll") for (int j = 0; j < 4; j++)                                    \
      acc[i][j] = (f32x4){0.f, 0.f, 0.f, 0.f};                                       \
  int lrow = lane >> 3;                              /* 0..7 within 8-row block */   \
  int lcol = ((lane & 7) ^ lrow) * 8;                /* XOR-swizzled source chunk */ \
  int sA = wave * 16;                                                                \
  int sB = wave * 32;                                                                \
  const unsigned short* aP0 = &A[(size_t)(m0 + sA + lrow) * K + lcol];               \
  const unsigned short* aP1 = aP0 + 8 * (size_t)K;                                   \
  const unsigned short* bP0 = &Bm[(size_t)(n0 + sB + lrow) * K + lcol];              \
  const unsigned short* bP1 = bP0 + 8 * (size_t)K;                                   \
  const unsigned short* bP2 = bP0 + 16 * (size_t)K;                                  \
  const unsigned short* bP3 = bP0 + 24 * (size_t)K;                                  \
  __builtin_amdgcn_global_load_lds(GL(aP0), LD(&As[0][(sA     ) * 64]), 16, 0, 0);   \
  __builtin_amdgcn_global_load_lds(GL(aP1), LD(&As[0][(sA +  8) * 64]), 16, 0, 0);   \
  __builtin_amdgcn_global_load_lds(GL(bP0), LD(&Bs[0][(sB     ) * 64]), 16, 0, 0);   \
  __builtin_amdgcn_global_load_lds(GL(bP1), LD(&Bs[0][(sB +  8) * 64]), 16, 0, 0);   \
  __builtin_amdgcn_global_load_lds(GL(bP2), LD(&Bs[0][(sB + 16) * 64]), 16, 0, 0);   \
  __builtin_amdgcn_global_load_lds(GL(bP3), LD(&Bs[0][(sB + 24) * 64]), 16, 0, 0);   \
  int swz = l16 & 7;                                                                 \
  int nk = K >> 6;                                                                   \
  for (int ki = 0; ki < nk; ki++) {                                                  \
    int cur = ki & 1, nxt = cur ^ 1;                                                 \
    __syncthreads();                                                                 \
    if (ki + 1 < nk) {                                                               \
      int k0 = (ki + 1) << 6;                                                        \
      __builtin_amdgcn_global_load_lds(GL(aP0 + k0), LD(&As[nxt][(sA     ) * 64]), 16, 0, 0); \
      __builtin_amdgcn_global_load_lds(GL(aP1 + k0), LD(&As[nxt][(sA +  8) * 64]), 16, 0, 0); \
      __builtin_amdgcn_global_load_lds(GL(bP0 + k0), LD(&Bs[nxt][(sB     ) * 64]), 16, 0, 0); \
      __builtin_amdgcn_global_load_lds(GL(bP1 + k0), LD(&Bs[nxt][(sB +  8) * 64]), 16, 0, 0); \
      __builtin_amdgcn_global_load_lds(GL(bP2 + k0), LD(&Bs[nxt][(sB + 16) * 64]), 16, 0, 0); \
      __builtin_amdgcn_global_load_lds(GL(bP3 + k0), LD(&Bs[nxt][(sB + 24) * 64]), 16, 0, 0); \
    }                                                                                \
    _Pragma("unroll") for (int p = 0; p < 2; p++) {                                  \
      bf16x8 af[2], bfr[4];                                                          \
      _Pragma("unroll") for (int i = 0; i < 2; i++)                                  \
        af[i] = *(const bf16x8*)&As[cur][(wm + i * 16 + l16) * 64 + (((p * 4 + quad) ^ swz) * 8)]; \
      _Pragma("unroll") for (int j = 0; j < 4; j++)                                  \
        bfr[j] = *(const bf16x8*)&Bs[cur][(wn + j * 16 + l16) * 64 + (((p * 4 + quad) ^ swz) * 8)]; \
      _Pragma("unroll") for (int i = 0; i < 2; i++)                                  \
        _Pragma("unroll") for (int j = 0; j < 4; j++)                                \
          acc[i][j] = __builtin_amdgcn_mfma_f32_16x16x32_bf16(af[i], bfr[j], acc[i][j], 0, 0, 0); \
    }                                                                                \
  }

// ---------------- gemm2: C[m,n] = sum_k A[m,k]*B[n,k], fp32 out ----------------
__global__ __launch_bounds__(256) void gemm_bt(const unsigned short* __restrict__ A,
                                               const unsigned short* __restrict__ Bm,
                                               float* __restrict__ C,
                                               int N, int K) {
  GEMM_PROLOG(A, Bm, K)
#pragma unroll
  for (int i = 0; i < 2; i++) {
#pragma unroll
    for (int j = 0; j < 4; j++) {
      int col = n0 + wn + j * 16 + l16;
#pragma unroll
      for (int r = 0; r < 4; r++) {
        int row = m0 + wm + i * 16 + quad * 4 + r;
        C[(size_t)row * N + col] = acc[i][j][r];
      }
    }
  }
}

// ---------------- gemm1 fused: qkv proj + RoPE + RMSNorm + gate*ve + V-TRANSPOSE, bf16 out ----------
// Q/K heads: RoPE+RMS epilogue as before. V blocks (n0>=1280, whole block is V): epilogue
// transposes the 64(bt) x 128(2 heads) tile through LDS (reusing Bs[0]: last K-iter reads
// only buffers [1]) and writes vt (B,NKV,HD,T) directly -> v_transpose kernel + vtmp deleted.
__global__ __launch_bounds__(256) void gemm_qkv(const unsigned short* __restrict__ A,
                                                const unsigned short* __restrict__ Bm,
                                                const float* __restrict__ ve,
                                                const float* __restrict__ cosb,
                                                const float* __restrict__ sinb,
                                                const float* __restrict__ gateArr,
                                                unsigned short* __restrict__ qa,
                                                unsigned short* __restrict__ ka,
                                                unsigned short* __restrict__ vt) {
  const int K = C_SZ;
  GEMM_PROLOG(A, Bm, K)

  int colbase = n0 + wn;   // multiple of 64
  if (colbase < 1280) {    // Q or K head
    int isQ = colbase < 1024;
    int h   = isQ ? (colbase >> 6) : ((colbase - 1024) >> 6);
    float scale = isQ ? (0.15f * 1.44269504088896f) : 1.2f;
    unsigned short* dst = isQ ? qa : ka;
    int nheads = isQ ? NH : NKV;
#pragma unroll
    for (int i = 0; i < 2; i++) {
#pragma unroll
      for (int r = 0; r < 4; r++) {
        int row = m0 + wm + i * 16 + quad * 4 + r;   // bt
        int t = row & (T_SZ - 1), b = row >> 11;
        float a10 = acc[i][0][r], a11 = acc[i][1][r];
        float a20 = acc[i][2][r], a21 = acc[i][3][r];
        float cv0 = cosb[t * 32 + l16],      sv0 = sinb[t * 32 + l16];
        float cv1 = cosb[t * 32 + 16 + l16], sv1 = sinb[t * 32 + 16 + l16];
        float o10 =  a10 * cv0 + a20 * sv0;
        float o11 =  a11 * cv1 + a21 * sv1;
        float o20 = -a10 * sv0 + a20 * cv0;
        float o21 = -a11 * sv1 + a21 * cv1;
        float ssq = o10 * o10 + o11 * o11 + o20 * o20 + o21 * o21;
        ssq += __shfl_xor(ssq, 1);
        ssq += __shfl_xor(ssq, 2);
        ssq += __shfl_xor(ssq, 4);
        ssq += __shfl_xor(ssq, 8);
        float rn = rsqrtf(ssq * (1.f / 64.f) + 1e-6f) * scale;
        size_t base = ((size_t)(b * nheads + h) * T_SZ + t) * HD;
        dst[base + l16]      = f2bf(o10 * rn);
        dst[base + 16 + l16] = f2bf(o11 * rn);
        dst[base + 32 + l16] = f2bf(o20 * rn);
        dst[base + 48 + l16] = f2bf(o21 * rn);
      }
    }
  } else {                 // V block: gate*ve add, transpose via LDS, write vt directly
    int kh  = (colbase - 1280) >> 6;                 // this wave's head
    int khb = (n0 - 1280) >> 6;                      // block's base head
    unsigned short* tile = (unsigned short*)&Bs[0][0];   // 64 x 128, stride 132 (8448 <= 16384)
    const int TS = 132;
    // phase 1: write [t_local][d2]; lanes: l16 contiguous (2/bank), quads 8 banks apart -> clean
#pragma unroll
    for (int i = 0; i < 2; i++) {
#pragma unroll
      for (int r = 0; r < 4; r++) {
        int rl  = wm + i * 16 + quad * 4 + r;        // t_local 0..63
        int row = m0 + rl;                           // bt
        float g = gateArr[row * 4 + kh];
#pragma unroll
        for (int j = 0; j < 4; j++) {
          int d = j * 16 + l16;
          float val = acc[i][j][r] + g * ve[(size_t)row * KVD + kh * HD + d];
          tile[rl * TS + wn + d] = f2bf(val);
        }
      }
    }
    __syncthreads();
    // phase 2: column gather (64 lanes span 128B -> 32 banks 2-way = free), coalesced vt rows
    int d2  = tid & 127;                             // 0..127 across both heads
    int seg = tid >> 7;                              // t half: 0,1
    int khw = khb + (d2 >> 6);
    int dd  = d2 & 63;
    int bb  = m0 >> 11;
    int tl0 = (m0 & (T_SZ - 1)) + seg * 32;
    unsigned short* dstp = &vt[((size_t)(bb * NKV + khw) * HD + dd) * T_SZ + tl0];
#pragma unroll
    for (int k4 = 0; k4 < 8; k4++) {
      ushort4 o;
      o.x = tile[(seg * 32 + k4 * 4 + 0) * TS + d2];
      o.y = tile[(seg * 32 + k4 * 4 + 1) * TS + d2];
      o.z = tile[(seg * 32 + k4 * 4 + 2) * TS + d2];
      o.w = tile[(seg * 32 + k4 * 4 + 3) * TS + d2];
      *(ushort4*)(dstp + k4 * 4) = o;
    }
  }
}

// ---------------- causal flash attention: Q=128, 8 waves x 16 q-rows, S^T trick ----------------
// Round-3 proven structure (best measured): dbuf single barrier, 512 threads, 16 waves/CU.
// + s_setprio(1) around MFMA clusters (T5: independent blocks/CU at different phases).
#define KST 72
#define PST 72
__global__ __launch_bounds__(512, 4) void attn(const unsigned short* __restrict__ qa,
                                               const unsigned short* __restrict__ ka,
                                               const unsigned short* __restrict__ vt,
                                               unsigned short* __restrict__ y) {
  // pair qt with 15-qt so co-resident blocks sum to equal work
  int bid = blockIdx.x;
  int half = bid >> 8, r = bid & 255;
  int qt = half ? (r & 15) : 15 - (r & 15);
  int bh = (half << 4) | (r >> 4);
  int b = bh >> 4, h = bh & 15;
  int kh = h >> 2;
  int tid = threadIdx.x;
  int wave = tid >> 6, lane = tid & 63;
  int quad = lane >> 4, l16 = lane & 15;

  __shared__ unsigned short Ks[2][64 * KST];   // [t_local][d]
  __shared__ unsigned short Vs[2][64 * KST];   // [d][t_local]
  __shared__ unsigned short Ps[128 * PST];     // [q_local][t_local]
  unsigned short* Pw = &Ps[(wave * 16) * PST];

  int qrow0 = qt * 128 + wave * 16;

  bf16x8 bq0, bq1;
  {
    int tq = qrow0 + l16;
    const unsigned short* qp = &qa[((size_t)(b * NH + h) * T_SZ + tq) * HD];
    bq0 = *(const bf16x8*)&qp[quad * 8];
    bq1 = *(const bf16x8*)&qp[32 + quad * 8];
  }

  const unsigned short one_bf = 0x3F80;
  bf16x8 vones = {(short)one_bf, (short)one_bf, (short)one_bf, (short)one_bf,
                  (short)one_bf, (short)one_bf, (short)one_bf, (short)one_bf};

  f32x4 oacc[4];
  f32x4 lacc = (f32x4){0.f, 0.f, 0.f, 0.f};
#pragma unroll
  for (int d = 0; d < 4; d++) oacc[d] = (f32x4){0.f, 0.f, 0.f, 0.f};

  int lr = tid >> 3;          // 0..63
  int lc = (tid & 7) * 8;     // 0..56 step 8

  const unsigned short* kbase = &ka[(size_t)(b * NKV + kh) * T_SZ * HD];
  const unsigned short* vbase = &vt[(size_t)(b * NKV + kh) * HD * T_SZ];

  int nj = 2 * qt + 2;

  {
    uint4 k0 = *(const uint4*)&kbase[(size_t)lr * HD + lc];
    uint4 v0 = *(const uint4*)&vbase[(size_t)lr * T_SZ + lc];
    *(uint4*)&Ks[0][lr * KST + lc] = k0;
    *(uint4*)&Vs[0][lr * KST + lc] = v0;
  }

  for (int j = 0; j < nj; j++) {
    int cur = j & 1, nxt = cur ^ 1;
    __syncthreads();   // buf[cur] writes visible; all prior reads drained

    uint4 k0, v0;
    bool pf = (j + 1 < nj);
    if (pf) {
      k0 = *(const uint4*)&kbase[(size_t)((j + 1) * 64 + lr) * HD + lc];
      v0 = *(const uint4*)&vbase[(size_t)lr * T_SZ + (j + 1) * 64 + lc];
    }

    // waves whose 16 q-rows all precede this K-block are fully masked -> skip compute
    bool active = (j * 64) <= (qrow0 + 15);

    if (active) {
      // S^T = K Q^T: D[m=t][n=q]; K-frags as A
      f32x4 st[4];
      __builtin_amdgcn_s_setprio(1);
#pragma unroll
      for (int tb = 0; tb < 4; tb++) {
        bf16x8 ak0 = *(const bf16x8*)&Ks[cur][(tb * 16 + l16) * KST + quad * 8];
        bf16x8 ak1 = *(const bf16x8*)&Ks[cur][(tb * 16 + l16) * KST + 32 + quad * 8];
        f32x4 s = (f32x4){0.f, 0.f, 0.f, 0.f};
        s = __builtin_amdgcn_mfma_f32_16x16x32_bf16(ak0, bq0, s, 0, 0, 0);
        s = __builtin_amdgcn_mfma_f32_16x16x32_bf16(ak1, bq1, s, 0, 0, 0);
        st[tb] = s;
      }
      __builtin_amdgcn_s_setprio(0);

      // mask + exp2 + packed b64 store of P[q][t] (per-wave region, no barrier needed)
      if (j * 64 + 63 > qrow0) {
        int qg = qrow0 + l16;
#pragma unroll
        for (int tb = 0; tb < 4; tb++) {
          int tg = j * 64 + tb * 16 + quad * 4;
#pragma unroll
          for (int i = 0; i < 4; i++) {
            if (tg + i > qg) st[tb][i] = -__builtin_inff();
          }
        }
      }
#pragma unroll
      for (int tb = 0; tb < 4; tb++) {
        ushort4 w;
        w.x = bftrunc(__builtin_amdgcn_exp2f(st[tb][0]));
        w.y = bftrunc(__builtin_amdgcn_exp2f(st[tb][1]));
        w.z = bftrunc(__builtin_amdgcn_exp2f(st[tb][2]));
        w.w = bftrunc(__builtin_amdgcn_exp2f(st[tb][3]));
        *(ushort4*)&Pw[l16 * PST + tb * 16 + quad * 4] = w;
      }

      bf16x8 ap0 = *(const bf16x8*)&Pw[l16 * PST + quad * 8];
      bf16x8 ap1 = *(const bf16x8*)&Pw[l16 * PST + 32 + quad * 8];
      __builtin_amdgcn_s_setprio(1);
      lacc = __builtin_amdgcn_mfma_f32_16x16x32_bf16(ap0, vones, lacc, 0, 0, 0);
      lacc = __builtin_amdgcn_mfma_f32_16x16x32_bf16(ap1, vones, lacc, 0, 0, 0);
#pragma unroll
      for (int d = 0; d < 4; d++) {
        bf16x8 bv0 = *(const bf16x8*)&Vs[cur][(d * 16 + l16) * KST + quad * 8];
        bf16x8 bv1 = *(const bf16x8*)&Vs[cur][(d * 16 + l16) * KST + 32 + quad * 8];
        oacc[d] = __builtin_amdgcn_mfma_f32_16x16x32_bf16(ap0, bv0, oacc[d], 0, 0, 0);
        oacc[d] = __builtin_amdgcn_mfma_f32_16x16x32_bf16(ap1, bv1, oacc[d], 0, 0, 0);
      }
      __builtin_amdgcn_s_setprio(0);
    }

    if (pf) {
      *(uint4*)&Ks[nxt][lr * KST + lc] = k0;
      *(uint4*)&Vs[nxt][lr * KST + lc] = v0;
    }
  }

#pragma unroll
  for (int i = 0; i < 4; i++) {
    int tq = qrow0 + quad * 4 + i;
    float inv = 1.f / lacc[i];
#pragma unroll
    for (int d = 0; d < 4; d++) {
      y[((size_t)(b * T_SZ) + tq) * C_SZ + h * HD + d * 16 + l16] = f2bf(oacc[d][i] * inv);
    }
  }
}

extern "C" void kernel_launch(void* const* d_in, const int* in_sizes, int n_in,
                              void* d_out, int out_size, void* d_ws, size_t ws_size,
                              hipStream_t stream) {
  const float* x    = (const float*)d_in[0];
  const float* ve   = (const float*)d_in[1];
  const float* cosb = (const float*)d_in[2];
  const float* sinb = (const float*)d_in[3];
  const float* Wq   = (const float*)d_in[4];
  const float* Wk   = (const float*)d_in[5];
  const float* Wv   = (const float*)d_in[6];
  const float* Wo   = (const float*)d_in[7];
  const float* Wg   = (const float*)d_in[8];
  float* out = (float*)d_out;

  const size_t MB = 1024 * 1024;
  char* ws = (char*)d_ws;
  unsigned short* xb    = (unsigned short*)(ws);             // 8 MB (reused as yb)
  unsigned short* wqkvb = (unsigned short*)(ws + 8 * MB);    // 3 MB
  unsigned short* wob   = (unsigned short*)(ws + 11 * MB);   // 2 MB
  unsigned short* qab   = (unsigned short*)(ws + 13 * MB);   // 8 MB
  unsigned short* kab   = (unsigned short*)(ws + 21 * MB);   // 2 MB
  unsigned short* vtb   = (unsigned short*)(ws + 23 * MB);   // 2 MB
  float*          gateA = (float*)(ws + 25 * MB);            // 64 KB
  unsigned short* yb    = xb;                                // reuse after gemm_qkv

  CvtArgs ca;
  ca.s0 = x;  ca.d0 = xb;
  ca.s1 = Wq; ca.d1 = wqkvb;
  ca.s2 = Wk; ca.d2 = wqkvb + 1024 * 1024;
  ca.s3 = Wv; ca.d3 = wqkvb + 1280 * 1024;
  ca.s4 = Wo; ca.d4 = wob;
  ca.x = x; ca.Wg = Wg; ca.gate = gateA;
  cvt_all<<<6720, 256, 0, stream>>>(ca);

  gemm_qkv<<<dim3(QKV_N / 128, (B_SZ * T_SZ) / 64), 256, 0, stream>>>(
      xb, wqkvb, ve, cosb, sinb, gateA, qab, kab, vtb);

  attn<<<512, 512, 0, stream>>>(qab, kab, vtb, yb);

  gemm_bt<<<dim3(C_SZ / 128, (B_SZ * T_SZ) / 64), 256, 0, stream>>>(
      yb, wob, out, C_SZ, C_SZ);
}